// Round 12
// baseline (399.140 us; speedup 1.0000x reference)
//
#include <hip/hip_runtime.h>

typedef __bf16 bf16_t;
typedef bf16_t bf16x4 __attribute__((ext_vector_type(4)));
typedef bf16_t bf16x8 __attribute__((ext_vector_type(8)));
typedef float floatx2 __attribute__((ext_vector_type(2)));
typedef float floatx4 __attribute__((ext_vector_type(4)));

#define MFMA16(a, b, c) __builtin_amdgcn_mfma_f32_16x16x32_bf16(a, b, c, 0, 0, 0)

__device__ __forceinline__ bf16x4 cvt4(float4 f) {
  bf16x4 o;
  o[0] = (bf16_t)f.x; o[1] = (bf16_t)f.y; o[2] = (bf16_t)f.z; o[3] = (bf16_t)f.w;
  return o;
}

// async global->LDS, 16 B per lane.
__device__ __forceinline__ void gl16(const bf16_t* g, void* l) {
  __builtin_amdgcn_global_load_lds(
      (const __attribute__((address_space(1))) unsigned int*)g,
      (__attribute__((address_space(3))) unsigned int*)l, 16, 0, 0);
}

// ---------------------------------------------------------------------------
// K_prep: fused fp32->bf16 converts (x, wqkv, wproj) + bias gather.
// Grid 3328: [0,2048) x cvt (grid-stride), [2048,2816) wqkv, [2816,3072)
// wproj, [3072,3328) bias gather.
// ---------------------------------------------------------------------------
__global__ __launch_bounds__(256) void k_prep(const float* __restrict__ x,
                                              bf16_t* __restrict__ xb,
                                              const float* __restrict__ qkvw,
                                              bf16_t* __restrict__ wqkvb,
                                              const float* __restrict__ projw,
                                              bf16_t* __restrict__ wpb,
                                              const int* __restrict__ rel_index,
                                              const float* __restrict__ table,
                                              bf16_t* __restrict__ bias) {
  const int b = blockIdx.x;
  if (b < 2048) {
    int i = b * 256 + threadIdx.x;
    for (; i < 4194304; i += 2048 * 256)
      ((bf16x4*)xb)[i] = cvt4(((const float4*)x)[i]);
  } else if (b < 2816) {
    int i = (b - 2048) * 256 + threadIdx.x;
    ((bf16x4*)wqkvb)[i] = cvt4(((const float4*)qkvw)[i]);
  } else if (b < 3072) {
    int i = (b - 2816) * 256 + threadIdx.x;
    ((bf16x4*)wpb)[i] = cvt4(((const float4*)projw)[i]);
  } else {
    int ij = (b - 3072) * 256 + threadIdx.x;
    int idx = rel_index[ij];
#pragma unroll
    for (int h = 0; h < 8; ++h)
      bias[h * 65536 + ij] = (bf16_t)table[idx * 8 + h];
  }
}

// ---------------------------------------------------------------------------
// K0: bias gather (fallback paths only).
// ---------------------------------------------------------------------------
__global__ __launch_bounds__(256) void k_bias(const int* __restrict__ rel_index,
                                              const float* __restrict__ table,
                                              bf16_t* __restrict__ bias) {
  int ij = blockIdx.x * 256 + threadIdx.x;
  int idx = rel_index[ij];
#pragma unroll
  for (int h = 0; h < 8; ++h)
    bias[h * 65536 + ij] = (bf16_t)table[idx * 8 + h];
}

// ---------------------------------------------------------------------------
// K1 v2: QKV GEMM, bf16 inputs, m97 recipe (unchanged).
// ---------------------------------------------------------------------------
__global__ __launch_bounds__(256) void k_qkv_b(const bf16_t* __restrict__ xb,
                                               const bf16_t* __restrict__ wb,
                                               const float* __restrict__ bqkv,
                                               bf16_t* __restrict__ q,
                                               bf16_t* __restrict__ k,
                                               bf16_t* __restrict__ v) {
  __shared__ __align__(16) bf16_t As[128 * 32];
  __shared__ __align__(16) bf16_t Bs[128 * 32];

  const int tid = threadIdx.x;
  const int blk = blockIdx.x;                   // flat 3072
  const int xcd = blk & 7, s = blk >> 3;        // 384 per XCD
  const int y = s % 12, mt = xcd * 32 + s / 12; // y-fast: A panel reused 12x
  const int m0 = mt * 128, n0 = y * 128;

  const bf16_t* asrc[2];
  const bf16_t* bsrc[2];
#pragma unroll
  for (int i = 0; i < 2; ++i) {
    int id = tid + 256 * i;
    int row = id >> 2, c8 = (id & 3) * 8;
    int r = m0 + row;
    int w = r >> 8, n = r & 255;
    int b = w >> 4, wh = (w >> 2) & 3, ww = w & 3;
    int rh = n >> 4, rw = n & 15;
    int l = wh * 1024 + rh * 64 + ww * 16 + rw;
    asrc[i] = xb + (size_t)(b * 4096 + l) * 512 + c8;
    bsrc[i] = wb + (size_t)(n0 + row) * 512 + c8;
  }
  char* ldsA = (char*)As + tid * 16;
  char* ldsB = (char*)Bs + tid * 16;

  const int lane = tid & 63, wid = tid >> 6;
  const int wm = (wid >> 1) * 64, wn = (wid & 1) * 64;
  const int lm = lane & 15, lq = lane >> 4;

  floatx4 acc[4][4] = {};

  for (int k0 = 0; k0 < 512; k0 += 32) {
    gl16(asrc[0] + k0, ldsA);
    gl16(asrc[1] + k0, ldsA + 4096);
    gl16(bsrc[0] + k0, ldsB);
    gl16(bsrc[1] + k0, ldsB + 4096);
    __syncthreads();
    bf16x8 af[4], bfr[4];
#pragma unroll
    for (int s4 = 0; s4 < 4; ++s4) {
      af[s4]  = *(const bf16x8*)&As[(wm + s4 * 16 + lm) * 32 + lq * 8];
      bfr[s4] = *(const bf16x8*)&Bs[(wn + s4 * 16 + lm) * 32 + lq * 8];
    }
#pragma unroll
    for (int ms = 0; ms < 4; ++ms)
#pragma unroll
      for (int ns = 0; ns < 4; ++ns)
        acc[ms][ns] = MFMA16(af[ms], bfr[ns], acc[ms][ns]);
    __syncthreads();
  }

#pragma unroll
  for (int ms = 0; ms < 4; ++ms) {
#pragma unroll
    for (int ns = 0; ns < 4; ++ns) {
      int col = n0 + wn + ns * 16 + lm;
      int sC = col >> 9, rem = col & 511;
      int hh = rem >> 6, d = rem & 63;
      bf16_t* dst = (sC == 0) ? q : (sC == 1) ? k : v;
      float bc = bqkv[col];
      float scale = (sC == 0) ? 0.125f : 1.0f;
#pragma unroll
      for (int r = 0; r < 4; ++r) {
        int row = m0 + wm + ms * 16 + lq * 4 + r;
        int w = row >> 8, n = row & 255;
        float val = (acc[ms][ns][r] + bc) * scale;
        dst[(size_t)((w * 8 + hh) * 256 + n) * 64 + d] = (bf16_t)val;
      }
    }
  }
}

// ---------------------------------------------------------------------------
// K1 fallback: original fp32-input QKV GEMM.
// ---------------------------------------------------------------------------
#define LDAB 40

__global__ __launch_bounds__(256) void k_qkv(const float* __restrict__ x,
                                             const float* __restrict__ wqkv,
                                             const float* __restrict__ bqkv,
                                             bf16_t* __restrict__ q,
                                             bf16_t* __restrict__ k,
                                             bf16_t* __restrict__ v) {
  __shared__ __align__(16) bf16_t As[128 * LDAB];
  __shared__ __align__(16) bf16_t Bs[128 * LDAB];

  const int tid = threadIdx.x;
  const int m0 = blockIdx.x * 128;
  const int n0 = blockIdx.y * 128;

  const float* aptr[4];
  const float* bptr[4];
#pragma unroll
  for (int i = 0; i < 4; ++i) {
    int id = tid + 256 * i;
    int row = id >> 3;
    int c4 = (id & 7) * 4;
    int r = m0 + row;
    int w = r >> 8, n = r & 255;
    int b = w >> 4, wh = (w >> 2) & 3, ww = w & 3;
    int rh = n >> 4, rw = n & 15;
    int l = wh * 1024 + rh * 64 + ww * 16 + rw;
    aptr[i] = x + (size_t)(b * 4096 + l) * 512 + c4;
    bptr[i] = wqkv + (size_t)(n0 + row) * 512 + c4;
  }

  const int lane = tid & 63, wid = tid >> 6;
  const int wm = (wid >> 1) * 64, wn = (wid & 1) * 64;
  const int lm = lane & 15, lq = lane >> 4;

  floatx4 acc[4][4] = {};

  for (int k0 = 0; k0 < 512; k0 += 32) {
#pragma unroll
    for (int i = 0; i < 4; ++i) {
      int id = tid + 256 * i;
      float4 av = *(const float4*)(aptr[i] + k0);
      float4 bv = *(const float4*)(bptr[i] + k0);
      *(bf16x4*)&As[(id >> 3) * LDAB + (id & 7) * 4] = cvt4(av);
      *(bf16x4*)&Bs[(id >> 3) * LDAB + (id & 7) * 4] = cvt4(bv);
    }
    __syncthreads();
    bf16x8 af[4], bfr[4];
#pragma unroll
    for (int s = 0; s < 4; ++s) {
      af[s]  = *(const bf16x8*)&As[(wm + s * 16 + lm) * LDAB + lq * 8];
      bfr[s] = *(const bf16x8*)&Bs[(wn + s * 16 + lm) * LDAB + lq * 8];
    }
#pragma unroll
    for (int ms = 0; ms < 4; ++ms)
#pragma unroll
      for (int ns = 0; ns < 4; ++ns)
        acc[ms][ns] = MFMA16(af[ms], bfr[ns], acc[ms][ns]);
    __syncthreads();
  }

#pragma unroll
  for (int ms = 0; ms < 4; ++ms) {
#pragma unroll
    for (int ns = 0; ns < 4; ++ns) {
      int col = n0 + wn + ns * 16 + lm;
      int s = col >> 9, rem = col & 511;
      int hh = rem >> 6, d = rem & 63;
      bf16_t* dst = (s == 0) ? q : (s == 1) ? k : v;
      float bc = bqkv[col];
      float scale = (s == 0) ? 0.125f : 1.0f;
#pragma unroll
      for (int r = 0; r < 4; ++r) {
        int row = m0 + wm + ms * 16 + lq * 4 + r;
        int w = row >> 8, n = row & 255;
        float val = (acc[ms][ns][r] + bc) * scale;
        dst[(size_t)((w * 8 + hh) * 256 + n) * 64 + d] = (bf16_t)val;
      }
    }
  }
}

// ---------------------------------------------------------------------------
// K2 v7: v6 + packed-pair conv. The 15-tap conv (240 scalar v_fma_f32 per
// thread-tile, ~quarter of kernel VALU at 46% busy) is computed two adjacent
// rows at a time as floatx2 -> v_pk_fma_f32 (VOP3P dual fp32), halving the
// conv instruction count. Rows r,r+1 share tap weight pws[j] with operands
// {sreg[r+j], sreg[r+1+j]}. Worst case compiler scalarizes -> identical to
// v6. Everything else unchanged.
// ---------------------------------------------------------------------------
__global__ __launch_bounds__(256, 4) void k_attn_t(const bf16_t* __restrict__ q,
                                                   const bf16_t* __restrict__ k,
                                                   const bf16_t* __restrict__ v,
                                                   bf16_t* __restrict__ o,
                                                   const bf16_t* __restrict__ bias,
                                                   const float* __restrict__ pe_w,
                                                   const float* __restrict__ pe_b) {
  __shared__ __align__(16) char pool[39904];
  __shared__ float pws[15];
  bf16_t* vbuf = (bf16_t*)pool;                // [256][68]  (phase A)
  float*  S    = (float*)pool;                 // [30][260]  (per-tile)
  bf16_t* Pt   = (bf16_t*)(pool + 31200);      // [16][272]  (per-tile)

  const int bh = blockIdx.x;                   // 1024: one block per (w,h)
  const int h = bh & 7;                        // dispatch round-robin -> h==XCD
  const bf16_t* qb = q + (size_t)bh * 16384;
  const bf16_t* kb = k + (size_t)bh * 16384;
  const bf16_t* vb = v + (size_t)bh * 16384;
  const bf16_t* bb = bias + (size_t)h * 65536;
  const int tid = threadIdx.x, lane = tid & 63, wid = tid >> 6;
  const int lm = lane & 15, lq = lane >> 4;
  const int dcol = wid * 16 + lm;
  const int c = tid;

  if (tid < 15) pws[tid] = pe_w[h * 15 + tid];
  const float peb = pe_b[h];

  // stage V -> LDS (once per block)
#pragma unroll
  for (int it = 0; it < 8; ++it) {
    int id = tid + 256 * it;
    int tok = id >> 3, d8 = (id & 7) * 8;
    *(bf16x8*)&vbuf[tok * 68 + d8] = *(const bf16x8*)(vb + tok * 64 + d8);
  }

  // K fragments: loop-invariant, hoisted
  bf16x8 b0[4], b1[4];
#pragma unroll
  for (int ns = 0; ns < 4; ++ns) {
    int tk = wid * 64 + ns * 16 + lm;
    b0[ns] = *(const bf16x8*)(kb + (size_t)tk * 64 + lq * 8);
    b1[ns] = *(const bf16x8*)(kb + (size_t)tk * 64 + 32 + lq * 8);
  }
  __syncthreads();                             // [A] vbuf ready

  // V B-fragments (once per block; reused for all 16 tiles)
  bf16x8 vf[8];
#pragma unroll
  for (int kt = 0; kt < 8; ++kt)
#pragma unroll
    for (int j2 = 0; j2 < 8; ++j2)
      vf[kt][j2] = vbuf[(kt * 32 + lq * 8 + j2) * 68 + dcol];

  __syncthreads();                             // [B] vbuf dead; S region live

  bf16x8 vones;
#pragma unroll
  for (int j2 = 0; j2 < 8; ++j2) vones[j2] = (bf16_t)1.0f;

  bf16_t* ob = o + (size_t)bh * 16384;

#pragma unroll 1
  for (int ti = 0; ti < 16; ++ti) {
    // Q fragments + bias rows per tile (L2-resident)
    const int base = ti * 16 - 7;
    bf16x8 a0[2], a1[2];
#pragma unroll
    for (int tt = 0; tt < 2; ++tt) {
      int qrow = base + tt * 16 + lm;
      qrow = qrow < 0 ? 0 : (qrow > 255 ? 255 : qrow);
      a0[tt] = *(const bf16x8*)(qb + (size_t)qrow * 64 + lq * 8);
      a1[tt] = *(const bf16x8*)(qb + (size_t)qrow * 64 + 32 + lq * 8);
    }
    bf16_t biasreg[16];
#pragma unroll
    for (int r = 0; r < 16; ++r)
      biasreg[r] = bb[(size_t)(ti * 16 + r) * 256 + c];

    // zero conv halo rows at window edges (own-wave columns only: col=tid)
    if (ti == 0)
#pragma unroll
      for (int r = 0; r < 7; ++r) S[r * 260 + tid] = 0.f;
    if (ti == 15)
#pragma unroll
      for (int r = 23; r < 30; ++r) S[r * 260 + tid] = 0.f;

    // S rows base..base+31 (local 0..31, keep 0..29), guarded stores
#pragma unroll
    for (int tt = 0; tt < 2; ++tt) {
#pragma unroll
      for (int ns = 0; ns < 4; ++ns) {
        floatx4 acc = {0.f, 0.f, 0.f, 0.f};
        acc = MFMA16(a0[tt], b0[ns], acc);
        acc = MFMA16(a1[tt], b1[ns], acc);
        int col = wid * 64 + ns * 16 + lm;
#pragma unroll
        for (int r = 0; r < 4; ++r) {
          int lr = tt * 16 + lq * 4 + r;
          bool ok = (lr < 30) && !(ti == 0 && lr < 7) && !(ti == 15 && lr > 22);
          if (ok) S[lr * 260 + col] = acc[r];
        }
      }
    }
    // no barrier: S cols are wave-private; same-wave DS ordering suffices

    // conv: 30 column values, 16 rows x 15 taps, two rows per packed FMA
    float sreg[30];
#pragma unroll
    for (int i = 0; i < 30; ++i) sreg[i] = S[i * 260 + c];
#pragma unroll
    for (int r2 = 0; r2 < 8; ++r2) {
      floatx2 acc;
      acc[0] = sreg[2 * r2 + 7] + peb + (float)biasreg[2 * r2];
      acc[1] = sreg[2 * r2 + 8] + peb + (float)biasreg[2 * r2 + 1];
#pragma unroll
      for (int j2 = 0; j2 < 15; ++j2) {
        floatx2 sv;
        sv[0] = sreg[2 * r2 + j2];
        sv[1] = sreg[2 * r2 + 1 + j2];
        acc += sv * pws[j2];                   // v_pk_fma_f32 target
      }
      float e0 = __expf(fminf(fmaxf(acc[0], -60.f), 60.f));
      float e1 = __expf(fminf(fmaxf(acc[1], -60.f), 60.f));
      Pt[(2 * r2) * 272 + c] = (bf16_t)e0;
      Pt[(2 * r2 + 1) * 272 + c] = (bf16_t)e1;
    }
    __syncthreads();                           // [D] Pt ready (cross-wave)

    // PV + row-sum via MFMA (ones B-fragment); O = O'/L
    floatx4 oacc = {0.f, 0.f, 0.f, 0.f};
    floatx4 lacc = {0.f, 0.f, 0.f, 0.f};
#pragma unroll
    for (int kt = 0; kt < 8; ++kt) {
      bf16x8 a = *(const bf16x8*)&Pt[lm * 272 + kt * 32 + lq * 8];
      oacc = MFMA16(a, vf[kt], oacc);
      lacc = MFMA16(a, vones, lacc);
    }
#pragma unroll
    for (int r = 0; r < 4; ++r)
      ob[(size_t)(ti * 16 + lq * 4 + r) * 64 + dcol] = (bf16_t)(oacc[r] / lacc[r]);
    __syncthreads();                           // [E] Pt safe to overwrite
  }
}

// ---------------------------------------------------------------------------
// K2 fallback (small ws): per-(w,h) serial, O in place of v.
// ---------------------------------------------------------------------------
__global__ __launch_bounds__(256) void k_attn_s(const bf16_t* __restrict__ q,
                                                const bf16_t* __restrict__ k,
                                                bf16_t* __restrict__ v_io,
                                                const bf16_t* __restrict__ bias,
                                                const float* __restrict__ pe_w,
                                                const float* __restrict__ pe_b) {
  __shared__ __align__(16) char pool[58368];
  __shared__ float redB[4][16];
  __shared__ float pws[15];
  bf16_t* vbuf = (bf16_t*)pool;
  float*  ring = (float*)pool;                 // [3][16][260]
  bf16_t* Pt   = (bf16_t*)(pool + 49920);      // [16][264]

  const int bh = blockIdx.x;
  const int h = bh & 7;
  const bf16_t* qb = q + (size_t)bh * 16384;
  const bf16_t* kb = k + (size_t)bh * 16384;
  bf16_t* vb = v_io + (size_t)bh * 16384;
  const bf16_t* bb = bias + (size_t)h * 65536;
  const int tid = threadIdx.x, lane = tid & 63, wid = tid >> 6;
  const int lm = lane & 15, lq = lane >> 4;
  const int dcol = wid * 16 + lm;

  if (tid < 15) pws[tid] = pe_w[h * 15 + tid];
  const float peb = pe_b[h];

#pragma unroll
  for (int it = 0; it < 8; ++it) {
    int id = tid + 256 * it;
    int tok = id >> 3, d8 = (id & 7) * 8;
    *(bf16x8*)&vbuf[tok * 68 + d8] = *(const bf16x8*)(vb + tok * 64 + d8);
  }
  __syncthreads();
  bf16x8 vf[8];
#pragma unroll
  for (int kt = 0; kt < 8; ++kt)
#pragma unroll
    for (int j = 0; j < 8; ++j)
      vf[kt][j] = vbuf[(kt * 32 + lq * 8 + j) * 68 + dcol];
  __syncthreads();

  bf16x8 b0[4], b1[4];
#pragma unroll
  for (int ns = 0; ns < 4; ++ns) {
    int tk = wid * 64 + ns * 16 + lm;
    b0[ns] = *(const bf16x8*)(kb + (size_t)tk * 64 + lq * 8);
    b1[ns] = *(const bf16x8*)(kb + (size_t)tk * 64 + 32 + lq * 8);
  }

  auto computeS = [&](int ti2) {
    if (ti2 >= 16) return;
    int slot = ti2 % 3;
    int tq = ti2 * 16 + lm;
    bf16x8 a0 = *(const bf16x8*)(qb + (size_t)tq * 64 + lq * 8);
    bf16x8 a1 = *(const bf16x8*)(qb + (size_t)tq * 64 + 32 + lq * 8);
#pragma unroll
    for (int ns = 0; ns < 4; ++ns) {
      floatx4 acc = {0.f, 0.f, 0.f, 0.f};
      acc = MFMA16(a0, b0[ns], acc);
      acc = MFMA16(a1, b1[ns], acc);
      int col = wid * 64 + ns * 16 + lm;
#pragma unroll
      for (int r = 0; r < 4; ++r)
        ring[(slot * 16 + lq * 4 + r) * 260 + col] = acc[r];
    }
  };

  computeS(0);
  const int c = tid;
  for (int ti = 0; ti < 16; ++ti) {
    computeS(ti + 1);
    __syncthreads();

    float p[16];
#pragma unroll
    for (int r = 0; r < 16; ++r) {
      int R = ti * 16 + r;
      float acc = ring[((R >> 4) % 3 * 16 + (R & 15)) * 260 + c] + peb +
                  (float)bb[(size_t)R * 256 + c];
#pragma unroll
      for (int j = 0; j < 15; ++j) {
        int R2 = R + j - 7;
        if (R2 >= 0 && R2 < 256)
          acc += ring[((R2 >> 4) % 3 * 16 + (R2 & 15)) * 260 + c] * pws[j];
      }
      p[r] = __expf(fminf(fmaxf(acc, -60.f), 60.f));
    }
#pragma unroll
    for (int r = 0; r < 16; ++r) {
      float s = p[r];
      for (int off = 32; off; off >>= 1) s += __shfl_xor(s, off);
      if (lane == 0) redB[wid][r] = s;
    }
    __syncthreads();
#pragma unroll
    for (int r = 0; r < 16; ++r) {
      float inv = 1.0f / (redB[0][r] + redB[1][r] + redB[2][r] + redB[3][r]);
      Pt[r * 264 + c] = (bf16_t)(p[r] * inv);
    }
    __syncthreads();

    floatx4 oacc = {0.f, 0.f, 0.f, 0.f};
#pragma unroll
    for (int kt = 0; kt < 8; ++kt) {
      bf16x8 a = *(const bf16x8*)&Pt[lm * 264 + kt * 32 + lq * 8];
      oacc = MFMA16(a, vf[kt], oacc);
    }
#pragma unroll
    for (int r = 0; r < 4; ++r)
      vb[(size_t)(ti * 16 + lq * 4 + r) * 64 + dcol] = (bf16_t)oacc[r];
  }
}

// ---------------------------------------------------------------------------
// K5 v2: proj GEMM, bf16 inputs (unchanged).
// ---------------------------------------------------------------------------
__global__ __launch_bounds__(256) void k_proj_b(const bf16_t* __restrict__ A,
                                                const bf16_t* __restrict__ Wpb,
                                                const float* __restrict__ bp,
                                                float* __restrict__ out) {
  __shared__ __align__(16) bf16_t As[128 * 32];
  __shared__ __align__(16) bf16_t Bs[128 * 32];

  const int tid = threadIdx.x;
  const int blk = blockIdx.x;                  // flat 1024
  const int xcd = blk & 7, s = blk >> 3;       // 128 per XCD
  const int y = s & 3, mt = xcd * 32 + (s >> 2);
  const int m0 = mt * 128, n0 = y * 128;

  const int lane = tid & 63, wid = tid >> 6;
  const int wm = (wid >> 1) * 64, wn = (wid & 1) * 64;
  const int lm = lane & 15, lq = lane >> 4;

  size_t abase[2];
  const bf16_t* bsrc[2];
#pragma unroll
  for (int i = 0; i < 2; ++i) {
    int id = tid + 256 * i;
    int row = id >> 2, c8 = (id & 3) * 8;
    int r = m0 + row;
    int w = r >> 8, n = r & 255;
    abase[i] = (size_t)w * 131072 + (size_t)n * 64 + c8;
    bsrc[i] = Wpb + (size_t)(n0 + row) * 512 + c8;
  }
  char* ldsA = (char*)As + tid * 16;
  char* ldsB = (char*)Bs + tid * 16;

  floatx4 acc[4][4] = {};

  for (int k0 = 0; k0 < 512; k0 += 32) {
    size_t koff = (size_t)(k0 >> 6) * 16384 + (k0 & 32);
    gl16(A + abase[0] + koff, ldsA);
    gl16(A + abase[1] + koff, ldsA + 4096);
    gl16(bsrc[0] + k0, ldsB);
    gl16(bsrc[1] + k0, ldsB + 4096);
    __syncthreads();
    bf16x8 af[4], bfr[4];
#pragma unroll
    for (int s4 = 0; s4 < 4; ++s4) {
      af[s4]  = *(const bf16x8*)&As[(wm + s4 * 16 + lm) * 32 + lq * 8];
      bfr[s4] = *(const bf16x8*)&Bs[(wn + s4 * 16 + lm) * 32 + lq * 8];
    }
#pragma unroll
    for (int ms = 0; ms < 4; ++ms)
#pragma unroll
      for (int ns = 0; ns < 4; ++ns)
        acc[ms][ns] = MFMA16(af[ms], bfr[ns], acc[ms][ns]);
    __syncthreads();
  }

#pragma unroll
  for (int ms = 0; ms < 4; ++ms) {
#pragma unroll
    for (int r = 0; r < 4; ++r) {
      int row = m0 + wm + ms * 16 + lq * 4 + r;
      int w = row >> 8, n = row & 255;
      int b = w >> 4, wh = (w >> 2) & 3, ww = w & 3;
      int rh = n >> 4, rw = n & 15;
      int l = wh * 1024 + rh * 64 + ww * 16 + rw;
      size_t obase = (size_t)(b * 4096 + l) * 512;
#pragma unroll
      for (int ns = 0; ns < 4; ++ns) {
        int col = n0 + wn + ns * 16 + lm;
        out[obase + col] = acc[ms][ns][r] + bp[col];
      }
    }
  }
}

// ---------------------------------------------------------------------------
// K5 fallback: fp32-Wp proj GEMM (original).
// ---------------------------------------------------------------------------
__global__ __launch_bounds__(256) void k_proj(const bf16_t* __restrict__ A,
                                              const float* __restrict__ Wp,
                                              const float* __restrict__ bp,
                                              float* __restrict__ out) {
  __shared__ __align__(16) bf16_t As[128 * LDAB];
  __shared__ __align__(16) bf16_t Bs[128 * LDAB];

  const int tid = threadIdx.x;
  const int m0 = blockIdx.x * 128;
  const int n0 = blockIdx.y * 128;
  const int lane = tid & 63, wid = tid >> 6;
  const int wm = (wid >> 1) * 64, wn = (wid & 1) * 64;
  const int lm = lane & 15, lq = lane >> 4;

  size_t abase[2];
#pragma unroll
  for (int i = 0; i < 2; ++i) {
    int id = tid + 256 * i;
    int r = m0 + (id >> 2);
    int w = r >> 8, n = r & 255;
    abase[i] = (size_t)w * 131072 + (size_t)n * 64 + (id & 3) * 8;
  }
  const float* bptr[4];
#pragma unroll
  for (int i = 0; i < 4; ++i) {
    int id = tid + 256 * i;
    bptr[i] = Wp + (size_t)(n0 + (id >> 3)) * 512 + (id & 7) * 4;
  }

  floatx4 acc[4][4] = {};

  for (int k0 = 0; k0 < 512; k0 += 32) {
#pragma unroll
    for (int i = 0; i < 2; ++i) {
      int id = tid + 256 * i;
      bf16x8 av = *(const bf16x8*)(A + abase[i] + (k0 >> 6) * 16384 + (k0 & 63));
      *(bf16x8*)&As[(id >> 2) * LDAB + (id & 3) * 8] = av;
    }
#pragma unroll
    for (int i = 0; i < 4; ++i) {
      int id = tid + 256 * i;
      float4 bv = *(const float4*)(bptr[i] + k0);
      *(bf16x4*)&Bs[(id >> 3) * LDAB + (id & 7) * 4] = cvt4(bv);
    }
    __syncthreads();
    bf16x8 af[4], bfr[4];
#pragma unroll
    for (int s = 0; s < 4; ++s) {
      af[s]  = *(const bf16x8*)&As[(wm + s * 16 + lm) * LDAB + lq * 8];
      bfr[s] = *(const bf16x8*)&Bs[(wn + s * 16 + lm) * LDAB + lq * 8];
    }
#pragma unroll
    for (int ms = 0; ms < 4; ++ms)
#pragma unroll
      for (int ns = 0; ns < 4; ++ns)
        acc[ms][ns] = MFMA16(af[ms], bfr[ns], acc[ms][ns]);
    __syncthreads();
  }

#pragma unroll
  for (int ms = 0; ms < 4; ++ms) {
#pragma unroll
    for (int r = 0; r < 4; ++r) {
      int row = m0 + wm + ms * 16 + lq * 4 + r;
      int w = row >> 8, n = row & 255;
      int b = w >> 4, wh = (w >> 2) & 3, ww = w & 3;
      int rh = n >> 4, rw = n & 15;
      int l = wh * 1024 + rh * 64 + ww * 16 + rw;
      size_t obase = (size_t)(b * 4096 + l) * 512;
#pragma unroll
      for (int ns = 0; ns < 4; ++ns) {
        int col = n0 + wn + ns * 16 + lm;
        out[obase + col] = acc[ms][ns][r] + bp[col];
      }
    }
  }
}

// ---------------------------------------------------------------------------
extern "C" void kernel_launch(void* const* d_in, const int* in_sizes, int n_in,
                              void* d_out, int out_size, void* d_ws, size_t ws_size,
                              hipStream_t stream) {
  const float* x     = (const float*)d_in[0];
  const float* qkvw  = (const float*)d_in[1];
  const float* qkvb  = (const float*)d_in[2];
  const float* projw = (const float*)d_in[3];
  const float* projb = (const float*)d_in[4];
  const float* rbt   = (const float*)d_in[5];
  const float* pew   = (const float*)d_in[6];
  const float* peb   = (const float*)d_in[7];
  const int*   ridx  = (const int*)d_in[8];
  float* out = (float*)d_out;

  char* ws = (char*)d_ws;
  bf16_t* bias = (bf16_t*)ws;                                //  1 MiB bf16
  bf16_t* q    = (bf16_t*)(ws + (2u << 20));                 // 32 MiB
  bf16_t* k    = (bf16_t*)(ws + (2u << 20) + 33554432u);     // 32 MiB
  bf16_t* v    = (bf16_t*)(ws + (2u << 20) + 67108864u);     // 32 MiB
  const size_t need  = 2097152u + 4u * 33554432u;            // 130 MiB
  bf16_t* xb    = (bf16_t*)(ws + 136314880u);                // @130 MiB, 32 MiB
  bf16_t* wqkvb = (bf16_t*)(ws + 169869312u);                // @162 MiB, 1.5 MiB
  bf16_t* wpb   = (bf16_t*)(ws + 171442176u);                // @163.5 MiB, 0.5 MiB
  const size_t need2 = 171966464u;                           // 164 MiB

  if (ws_size >= need2) {
    k_prep<<<3328, 256, 0, stream>>>(x, xb, qkvw, wqkvb, projw, wpb,
                                     ridx, rbt, bias);
    bf16_t* o = (bf16_t*)(ws + (2u << 20) + 100663296u);     // @98 MiB
    k_qkv_b<<<3072, 256, 0, stream>>>(xb, wqkvb, qkvb, q, k, v);
    k_attn_t<<<1024, 256, 0, stream>>>(q, k, v, o, bias, pew, peb);
    k_proj_b<<<1024, 256, 0, stream>>>(o, wpb, projb, out);
  } else if (ws_size >= need) {
    k_bias<<<256, 256, 0, stream>>>(ridx, rbt, bias);
    bf16_t* o = (bf16_t*)(ws + (2u << 20) + 100663296u);     // @98 MiB
    k_qkv<<<dim3(256, 12), 256, 0, stream>>>(x, qkvw, qkvb, q, k, v);
    k_attn_t<<<1024, 256, 0, stream>>>(q, k, v, o, bias, pew, peb);
    k_proj<<<dim3(256, 4), 256, 0, stream>>>(o, projw, projb, out);
  } else {
    k_bias<<<256, 256, 0, stream>>>(ridx, rbt, bias);
    k_qkv<<<dim3(256, 12), 256, 0, stream>>>(x, qkvw, qkvb, q, k, v);
    k_attn_s<<<1024, 256, 0, stream>>>(q, k, v, bias, pew, peb);
    k_proj<<<dim3(256, 4), 256, 0, stream>>>(v, projw, projb, out);
  }
}

// Round 14
// 338.747 us; speedup vs baseline: 1.1783x; 1.1783x over previous
//
#include <hip/hip_runtime.h>

typedef __bf16 bf16_t;
typedef bf16_t bf16x4 __attribute__((ext_vector_type(4)));
typedef bf16_t bf16x8 __attribute__((ext_vector_type(8)));
typedef float floatx4 __attribute__((ext_vector_type(4)));

#define MFMA16(a, b, c) __builtin_amdgcn_mfma_f32_16x16x32_bf16(a, b, c, 0, 0, 0)

__device__ __forceinline__ bf16x4 cvt4(float4 f) {
  bf16x4 o;
  o[0] = (bf16_t)f.x; o[1] = (bf16_t)f.y; o[2] = (bf16_t)f.z; o[3] = (bf16_t)f.w;
  return o;
}

// async global->LDS, 16 B per lane.
__device__ __forceinline__ void gl16(const bf16_t* g, void* l) {
  __builtin_amdgcn_global_load_lds(
      (const __attribute__((address_space(1))) unsigned int*)g,
      (__attribute__((address_space(3))) unsigned int*)l, 16, 0, 0);
}

// ---------------------------------------------------------------------------
// K_prep: fused fp32->bf16 converts (x, wqkv, wproj) + bias gather.
// Grid 3328: [0,2048) x cvt (grid-stride), [2048,2816) wqkv, [2816,3072)
// wproj, [3072,3328) bias gather.
// ---------------------------------------------------------------------------
__global__ __launch_bounds__(256) void k_prep(const float* __restrict__ x,
                                              bf16_t* __restrict__ xb,
                                              const float* __restrict__ qkvw,
                                              bf16_t* __restrict__ wqkvb,
                                              const float* __restrict__ projw,
                                              bf16_t* __restrict__ wpb,
                                              const int* __restrict__ rel_index,
                                              const float* __restrict__ table,
                                              bf16_t* __restrict__ bias) {
  const int b = blockIdx.x;
  if (b < 2048) {
    int i = b * 256 + threadIdx.x;
    for (; i < 4194304; i += 2048 * 256)
      ((bf16x4*)xb)[i] = cvt4(((const float4*)x)[i]);
  } else if (b < 2816) {
    int i = (b - 2048) * 256 + threadIdx.x;
    ((bf16x4*)wqkvb)[i] = cvt4(((const float4*)qkvw)[i]);
  } else if (b < 3072) {
    int i = (b - 2816) * 256 + threadIdx.x;
    ((bf16x4*)wpb)[i] = cvt4(((const float4*)projw)[i]);
  } else {
    int ij = (b - 3072) * 256 + threadIdx.x;
    int idx = rel_index[ij];
#pragma unroll
    for (int h = 0; h < 8; ++h)
      bias[h * 65536 + ij] = (bf16_t)table[idx * 8 + h];
  }
}

// ---------------------------------------------------------------------------
// K0: bias gather (fallback paths only).
// ---------------------------------------------------------------------------
__global__ __launch_bounds__(256) void k_bias(const int* __restrict__ rel_index,
                                              const float* __restrict__ table,
                                              bf16_t* __restrict__ bias) {
  int ij = blockIdx.x * 256 + threadIdx.x;
  int idx = rel_index[ij];
#pragma unroll
  for (int h = 0; h < 8; ++h)
    bias[h * 65536 + ij] = (bf16_t)table[idx * 8 + h];
}

// ---------------------------------------------------------------------------
// K1 v2: QKV GEMM, bf16 inputs, m97 recipe (unchanged).
// ---------------------------------------------------------------------------
__global__ __launch_bounds__(256) void k_qkv_b(const bf16_t* __restrict__ xb,
                                               const bf16_t* __restrict__ wb,
                                               const float* __restrict__ bqkv,
                                               bf16_t* __restrict__ q,
                                               bf16_t* __restrict__ k,
                                               bf16_t* __restrict__ v) {
  __shared__ __align__(16) bf16_t As[128 * 32];
  __shared__ __align__(16) bf16_t Bs[128 * 32];

  const int tid = threadIdx.x;
  const int blk = blockIdx.x;                   // flat 3072
  const int xcd = blk & 7, s = blk >> 3;        // 384 per XCD
  const int y = s % 12, mt = xcd * 32 + s / 12; // y-fast: A panel reused 12x
  const int m0 = mt * 128, n0 = y * 128;

  const bf16_t* asrc[2];
  const bf16_t* bsrc[2];
#pragma unroll
  for (int i = 0; i < 2; ++i) {
    int id = tid + 256 * i;
    int row = id >> 2, c8 = (id & 3) * 8;
    int r = m0 + row;
    int w = r >> 8, n = r & 255;
    int b = w >> 4, wh = (w >> 2) & 3, ww = w & 3;
    int rh = n >> 4, rw = n & 15;
    int l = wh * 1024 + rh * 64 + ww * 16 + rw;
    asrc[i] = xb + (size_t)(b * 4096 + l) * 512 + c8;
    bsrc[i] = wb + (size_t)(n0 + row) * 512 + c8;
  }
  char* ldsA = (char*)As + tid * 16;
  char* ldsB = (char*)Bs + tid * 16;

  const int lane = tid & 63, wid = tid >> 6;
  const int wm = (wid >> 1) * 64, wn = (wid & 1) * 64;
  const int lm = lane & 15, lq = lane >> 4;

  floatx4 acc[4][4] = {};

  for (int k0 = 0; k0 < 512; k0 += 32) {
    gl16(asrc[0] + k0, ldsA);
    gl16(asrc[1] + k0, ldsA + 4096);
    gl16(bsrc[0] + k0, ldsB);
    gl16(bsrc[1] + k0, ldsB + 4096);
    __syncthreads();
    bf16x8 af[4], bfr[4];
#pragma unroll
    for (int s4 = 0; s4 < 4; ++s4) {
      af[s4]  = *(const bf16x8*)&As[(wm + s4 * 16 + lm) * 32 + lq * 8];
      bfr[s4] = *(const bf16x8*)&Bs[(wn + s4 * 16 + lm) * 32 + lq * 8];
    }
#pragma unroll
    for (int ms = 0; ms < 4; ++ms)
#pragma unroll
      for (int ns = 0; ns < 4; ++ns)
        acc[ms][ns] = MFMA16(af[ms], bfr[ns], acc[ms][ns]);
    __syncthreads();
  }

#pragma unroll
  for (int ms = 0; ms < 4; ++ms) {
#pragma unroll
    for (int ns = 0; ns < 4; ++ns) {
      int col = n0 + wn + ns * 16 + lm;
      int sC = col >> 9, rem = col & 511;
      int hh = rem >> 6, d = rem & 63;
      bf16_t* dst = (sC == 0) ? q : (sC == 1) ? k : v;
      float bc = bqkv[col];
      float scale = (sC == 0) ? 0.125f : 1.0f;
#pragma unroll
      for (int r = 0; r < 4; ++r) {
        int row = m0 + wm + ms * 16 + lq * 4 + r;
        int w = row >> 8, n = row & 255;
        float val = (acc[ms][ns][r] + bc) * scale;
        dst[(size_t)((w * 8 + hh) * 256 + n) * 64 + d] = (bf16_t)val;
      }
    }
  }
}

// ---------------------------------------------------------------------------
// K1 fallback: original fp32-input QKV GEMM.
// ---------------------------------------------------------------------------
#define LDAB 40

__global__ __launch_bounds__(256) void k_qkv(const float* __restrict__ x,
                                             const float* __restrict__ wqkv,
                                             const float* __restrict__ bqkv,
                                             bf16_t* __restrict__ q,
                                             bf16_t* __restrict__ k,
                                             bf16_t* __restrict__ v) {
  __shared__ __align__(16) bf16_t As[128 * LDAB];
  __shared__ __align__(16) bf16_t Bs[128 * LDAB];

  const int tid = threadIdx.x;
  const int m0 = blockIdx.x * 128;
  const int n0 = blockIdx.y * 128;

  const float* aptr[4];
  const float* bptr[4];
#pragma unroll
  for (int i = 0; i < 4; ++i) {
    int id = tid + 256 * i;
    int row = id >> 3;
    int c4 = (id & 7) * 4;
    int r = m0 + row;
    int w = r >> 8, n = r & 255;
    int b = w >> 4, wh = (w >> 2) & 3, ww = w & 3;
    int rh = n >> 4, rw = n & 15;
    int l = wh * 1024 + rh * 64 + ww * 16 + rw;
    aptr[i] = x + (size_t)(b * 4096 + l) * 512 + c4;
    bptr[i] = wqkv + (size_t)(n0 + row) * 512 + c4;
  }

  const int lane = tid & 63, wid = tid >> 6;
  const int wm = (wid >> 1) * 64, wn = (wid & 1) * 64;
  const int lm = lane & 15, lq = lane >> 4;

  floatx4 acc[4][4] = {};

  for (int k0 = 0; k0 < 512; k0 += 32) {
#pragma unroll
    for (int i = 0; i < 4; ++i) {
      int id = tid + 256 * i;
      float4 av = *(const float4*)(aptr[i] + k0);
      float4 bv = *(const float4*)(bptr[i] + k0);
      *(bf16x4*)&As[(id >> 3) * LDAB + (id & 7) * 4] = cvt4(av);
      *(bf16x4*)&Bs[(id >> 3) * LDAB + (id & 7) * 4] = cvt4(bv);
    }
    __syncthreads();
    bf16x8 af[4], bfr[4];
#pragma unroll
    for (int s = 0; s < 4; ++s) {
      af[s]  = *(const bf16x8*)&As[(wm + s * 16 + lm) * LDAB + lq * 8];
      bfr[s] = *(const bf16x8*)&Bs[(wn + s * 16 + lm) * LDAB + lq * 8];
    }
#pragma unroll
    for (int ms = 0; ms < 4; ++ms)
#pragma unroll
      for (int ns = 0; ns < 4; ++ns)
        acc[ms][ns] = MFMA16(af[ms], bfr[ns], acc[ms][ns]);
    __syncthreads();
  }

#pragma unroll
  for (int ms = 0; ms < 4; ++ms) {
#pragma unroll
    for (int ns = 0; ns < 4; ++ns) {
      int col = n0 + wn + ns * 16 + lm;
      int s = col >> 9, rem = col & 511;
      int hh = rem >> 6, d = rem & 63;
      bf16_t* dst = (s == 0) ? q : (s == 1) ? k : v;
      float bc = bqkv[col];
      float scale = (s == 0) ? 0.125f : 1.0f;
#pragma unroll
      for (int r = 0; r < 4; ++r) {
        int row = m0 + wm + ms * 16 + lq * 4 + r;
        int w = row >> 8, n = row & 255;
        float val = (acc[ms][ns][r] + bc) * scale;
        dst[(size_t)((w * 8 + hh) * 256 + n) * 64 + d] = (bf16_t)val;
      }
    }
  }
}

// ---------------------------------------------------------------------------
// K2 v8: v6 scalar conv RESTORED (v7's packed floatx2 conv spilled to
// scratch: FETCH 57->406 MB, dur 113->177. Reverted.) Plus T5 setprio(1)
// around the two MFMA clusters: 4 independent blocks/CU at different phases
// -> scheduler can favor MFMA-entering waves over conv-VALU waves (m191
// attn regime, +4-7%; NOT the lockstep-GEMM null case).
// ---------------------------------------------------------------------------
__global__ __launch_bounds__(256, 4) void k_attn_t(const bf16_t* __restrict__ q,
                                                   const bf16_t* __restrict__ k,
                                                   const bf16_t* __restrict__ v,
                                                   bf16_t* __restrict__ o,
                                                   const bf16_t* __restrict__ bias,
                                                   const float* __restrict__ pe_w,
                                                   const float* __restrict__ pe_b) {
  __shared__ __align__(16) char pool[39904];
  __shared__ float pws[15];
  bf16_t* vbuf = (bf16_t*)pool;                // [256][68]  (phase A)
  float*  S    = (float*)pool;                 // [30][260]  (per-tile)
  bf16_t* Pt   = (bf16_t*)(pool + 31200);      // [16][272]  (per-tile)

  const int bh = blockIdx.x;                   // 1024: one block per (w,h)
  const int h = bh & 7;                        // dispatch round-robin -> h==XCD
  const bf16_t* qb = q + (size_t)bh * 16384;
  const bf16_t* kb = k + (size_t)bh * 16384;
  const bf16_t* vb = v + (size_t)bh * 16384;
  const bf16_t* bb = bias + (size_t)h * 65536;
  const int tid = threadIdx.x, lane = tid & 63, wid = tid >> 6;
  const int lm = lane & 15, lq = lane >> 4;
  const int dcol = wid * 16 + lm;
  const int c = tid;

  if (tid < 15) pws[tid] = pe_w[h * 15 + tid];
  const float peb = pe_b[h];

  // stage V -> LDS (once per block)
#pragma unroll
  for (int it = 0; it < 8; ++it) {
    int id = tid + 256 * it;
    int tok = id >> 3, d8 = (id & 7) * 8;
    *(bf16x8*)&vbuf[tok * 68 + d8] = *(const bf16x8*)(vb + tok * 64 + d8);
  }

  // K fragments: loop-invariant, hoisted
  bf16x8 b0[4], b1[4];
#pragma unroll
  for (int ns = 0; ns < 4; ++ns) {
    int tk = wid * 64 + ns * 16 + lm;
    b0[ns] = *(const bf16x8*)(kb + (size_t)tk * 64 + lq * 8);
    b1[ns] = *(const bf16x8*)(kb + (size_t)tk * 64 + 32 + lq * 8);
  }
  __syncthreads();                             // [A] vbuf ready

  // V B-fragments (once per block; reused for all 16 tiles)
  bf16x8 vf[8];
#pragma unroll
  for (int kt = 0; kt < 8; ++kt)
#pragma unroll
    for (int j2 = 0; j2 < 8; ++j2)
      vf[kt][j2] = vbuf[(kt * 32 + lq * 8 + j2) * 68 + dcol];

  __syncthreads();                             // [B] vbuf dead; S region live

  bf16x8 vones;
#pragma unroll
  for (int j2 = 0; j2 < 8; ++j2) vones[j2] = (bf16_t)1.0f;

  bf16_t* ob = o + (size_t)bh * 16384;

#pragma unroll 1
  for (int ti = 0; ti < 16; ++ti) {
    // Q fragments + bias rows per tile (L2-resident)
    const int base = ti * 16 - 7;
    bf16x8 a0[2], a1[2];
#pragma unroll
    for (int tt = 0; tt < 2; ++tt) {
      int qrow = base + tt * 16 + lm;
      qrow = qrow < 0 ? 0 : (qrow > 255 ? 255 : qrow);
      a0[tt] = *(const bf16x8*)(qb + (size_t)qrow * 64 + lq * 8);
      a1[tt] = *(const bf16x8*)(qb + (size_t)qrow * 64 + 32 + lq * 8);
    }
    bf16_t biasreg[16];
#pragma unroll
    for (int r = 0; r < 16; ++r)
      biasreg[r] = bb[(size_t)(ti * 16 + r) * 256 + c];

    // zero conv halo rows at window edges (own-wave columns only: col=tid)
    if (ti == 0)
#pragma unroll
      for (int r = 0; r < 7; ++r) S[r * 260 + tid] = 0.f;
    if (ti == 15)
#pragma unroll
      for (int r = 23; r < 30; ++r) S[r * 260 + tid] = 0.f;

    // S rows base..base+31 (local 0..31, keep 0..29), guarded stores
    __builtin_amdgcn_s_setprio(1);
#pragma unroll
    for (int tt = 0; tt < 2; ++tt) {
#pragma unroll
      for (int ns = 0; ns < 4; ++ns) {
        floatx4 acc = {0.f, 0.f, 0.f, 0.f};
        acc = MFMA16(a0[tt], b0[ns], acc);
        acc = MFMA16(a1[tt], b1[ns], acc);
        int col = wid * 64 + ns * 16 + lm;
#pragma unroll
        for (int r = 0; r < 4; ++r) {
          int lr = tt * 16 + lq * 4 + r;
          bool ok = (lr < 30) && !(ti == 0 && lr < 7) && !(ti == 15 && lr > 22);
          if (ok) S[lr * 260 + col] = acc[r];
        }
      }
    }
    __builtin_amdgcn_s_setprio(0);
    // no barrier: S cols are wave-private; same-wave DS ordering suffices

    // conv from registers: 30 column values, 16 rows x 15 taps (scalar)
    float sreg[30];
#pragma unroll
    for (int i = 0; i < 30; ++i) sreg[i] = S[i * 260 + c];
    float p[16];
#pragma unroll
    for (int r = 0; r < 16; ++r) {
      float acc = sreg[r + 7] + peb + (float)biasreg[r];
#pragma unroll
      for (int j2 = 0; j2 < 15; ++j2)
        acc += sreg[r + j2] * pws[j2];
      p[r] = __expf(fminf(fmaxf(acc, -60.f), 60.f));  // unnormalized
    }
#pragma unroll
    for (int r = 0; r < 16; ++r)
      Pt[r * 272 + c] = (bf16_t)p[r];
    __syncthreads();                           // [D] Pt ready (cross-wave)

    // PV + row-sum via MFMA (ones B-fragment); O = O'/L
    floatx4 oacc = {0.f, 0.f, 0.f, 0.f};
    floatx4 lacc = {0.f, 0.f, 0.f, 0.f};
    __builtin_amdgcn_s_setprio(1);
#pragma unroll
    for (int kt = 0; kt < 8; ++kt) {
      bf16x8 a = *(const bf16x8*)&Pt[lm * 272 + kt * 32 + lq * 8];
      oacc = MFMA16(a, vf[kt], oacc);
      lacc = MFMA16(a, vones, lacc);
    }
    __builtin_amdgcn_s_setprio(0);
#pragma unroll
    for (int r = 0; r < 4; ++r)
      ob[(size_t)(ti * 16 + lq * 4 + r) * 64 + dcol] = (bf16_t)(oacc[r] / lacc[r]);
    __syncthreads();                           // [E] Pt safe to overwrite
  }
}

// ---------------------------------------------------------------------------
// K2 fallback (small ws): per-(w,h) serial, O in place of v.
// ---------------------------------------------------------------------------
__global__ __launch_bounds__(256) void k_attn_s(const bf16_t* __restrict__ q,
                                                const bf16_t* __restrict__ k,
                                                bf16_t* __restrict__ v_io,
                                                const bf16_t* __restrict__ bias,
                                                const float* __restrict__ pe_w,
                                                const float* __restrict__ pe_b) {
  __shared__ __align__(16) char pool[58368];
  __shared__ float redB[4][16];
  __shared__ float pws[15];
  bf16_t* vbuf = (bf16_t*)pool;
  float*  ring = (float*)pool;                 // [3][16][260]
  bf16_t* Pt   = (bf16_t*)(pool + 49920);      // [16][264]

  const int bh = blockIdx.x;
  const int h = bh & 7;
  const bf16_t* qb = q + (size_t)bh * 16384;
  const bf16_t* kb = k + (size_t)bh * 16384;
  bf16_t* vb = v_io + (size_t)bh * 16384;
  const bf16_t* bb = bias + (size_t)h * 65536;
  const int tid = threadIdx.x, lane = tid & 63, wid = tid >> 6;
  const int lm = lane & 15, lq = lane >> 4;
  const int dcol = wid * 16 + lm;

  if (tid < 15) pws[tid] = pe_w[h * 15 + tid];
  const float peb = pe_b[h];

#pragma unroll
  for (int it = 0; it < 8; ++it) {
    int id = tid + 256 * it;
    int tok = id >> 3, d8 = (id & 7) * 8;
    *(bf16x8*)&vbuf[tok * 68 + d8] = *(const bf16x8*)(vb + tok * 64 + d8);
  }
  __syncthreads();
  bf16x8 vf[8];
#pragma unroll
  for (int kt = 0; kt < 8; ++kt)
#pragma unroll
    for (int j = 0; j < 8; ++j)
      vf[kt][j] = vbuf[(kt * 32 + lq * 8 + j) * 68 + dcol];
  __syncthreads();

  bf16x8 b0[4], b1[4];
#pragma unroll
  for (int ns = 0; ns < 4; ++ns) {
    int tk = wid * 64 + ns * 16 + lm;
    b0[ns] = *(const bf16x8*)(kb + (size_t)tk * 64 + lq * 8);
    b1[ns] = *(const bf16x8*)(kb + (size_t)tk * 64 + 32 + lq * 8);
  }

  auto computeS = [&](int ti2) {
    if (ti2 >= 16) return;
    int slot = ti2 % 3;
    int tq = ti2 * 16 + lm;
    bf16x8 a0 = *(const bf16x8*)(qb + (size_t)tq * 64 + lq * 8);
    bf16x8 a1 = *(const bf16x8*)(qb + (size_t)tq * 64 + 32 + lq * 8);
#pragma unroll
    for (int ns = 0; ns < 4; ++ns) {
      floatx4 acc = {0.f, 0.f, 0.f, 0.f};
      acc = MFMA16(a0, b0[ns], acc);
      acc = MFMA16(a1, b1[ns], acc);
      int col = wid * 64 + ns * 16 + lm;
#pragma unroll
      for (int r = 0; r < 4; ++r)
        ring[(slot * 16 + lq * 4 + r) * 260 + col] = acc[r];
    }
  };

  computeS(0);
  const int c = tid;
  for (int ti = 0; ti < 16; ++ti) {
    computeS(ti + 1);
    __syncthreads();

    float p[16];
#pragma unroll
    for (int r = 0; r < 16; ++r) {
      int R = ti * 16 + r;
      float acc = ring[((R >> 4) % 3 * 16 + (R & 15)) * 260 + c] + peb +
                  (float)bb[(size_t)R * 256 + c];
#pragma unroll
      for (int j = 0; j < 15; ++j) {
        int R2 = R + j - 7;
        if (R2 >= 0 && R2 < 256)
          acc += ring[((R2 >> 4) % 3 * 16 + (R2 & 15)) * 260 + c] * pws[j];
      }
      p[r] = __expf(fminf(fmaxf(acc, -60.f), 60.f));
    }
#pragma unroll
    for (int r = 0; r < 16; ++r) {
      float s = p[r];
      for (int off = 32; off; off >>= 1) s += __shfl_xor(s, off);
      if (lane == 0) redB[wid][r] = s;
    }
    __syncthreads();
#pragma unroll
    for (int r = 0; r < 16; ++r) {
      float inv = 1.0f / (redB[0][r] + redB[1][r] + redB[2][r] + redB[3][r]);
      Pt[r * 264 + c] = (bf16_t)(p[r] * inv);
    }
    __syncthreads();

    floatx4 oacc = {0.f, 0.f, 0.f, 0.f};
#pragma unroll
    for (int kt = 0; kt < 8; ++kt) {
      bf16x8 a = *(const bf16x8*)&Pt[lm * 264 + kt * 32 + lq * 8];
      oacc = MFMA16(a, vf[kt], oacc);
    }
#pragma unroll
    for (int r = 0; r < 4; ++r)
      vb[(size_t)(ti * 16 + lq * 4 + r) * 64 + dcol] = (bf16_t)oacc[r];
  }
}

// ---------------------------------------------------------------------------
// K5 v2: proj GEMM, bf16 inputs (unchanged).
// ---------------------------------------------------------------------------
__global__ __launch_bounds__(256) void k_proj_b(const bf16_t* __restrict__ A,
                                                const bf16_t* __restrict__ Wpb,
                                                const float* __restrict__ bp,
                                                float* __restrict__ out) {
  __shared__ __align__(16) bf16_t As[128 * 32];
  __shared__ __align__(16) bf16_t Bs[128 * 32];

  const int tid = threadIdx.x;
  const int blk = blockIdx.x;                  // flat 1024
  const int xcd = blk & 7, s = blk >> 3;       // 128 per XCD
  const int y = s & 3, mt = xcd * 32 + (s >> 2);
  const int m0 = mt * 128, n0 = y * 128;

  const int lane = tid & 63, wid = tid >> 6;
  const int wm = (wid >> 1) * 64, wn = (wid & 1) * 64;
  const int lm = lane & 15, lq = lane >> 4;

  size_t abase[2];
  const bf16_t* bsrc[2];
#pragma unroll
  for (int i = 0; i < 2; ++i) {
    int id = tid + 256 * i;
    int row = id >> 2, c8 = (id & 3) * 8;
    int r = m0 + row;
    int w = r >> 8, n = r & 255;
    abase[i] = (size_t)w * 131072 + (size_t)n * 64 + c8;
    bsrc[i] = Wpb + (size_t)(n0 + row) * 512 + c8;
  }
  char* ldsA = (char*)As + tid * 16;
  char* ldsB = (char*)Bs + tid * 16;

  floatx4 acc[4][4] = {};

  for (int k0 = 0; k0 < 512; k0 += 32) {
    size_t koff = (size_t)(k0 >> 6) * 16384 + (k0 & 32);
    gl16(A + abase[0] + koff, ldsA);
    gl16(A + abase[1] + koff, ldsA + 4096);
    gl16(bsrc[0] + k0, ldsB);
    gl16(bsrc[1] + k0, ldsB + 4096);
    __syncthreads();
    bf16x8 af[4], bfr[4];
#pragma unroll
    for (int s4 = 0; s4 < 4; ++s4) {
      af[s4]  = *(const bf16x8*)&As[(wm + s4 * 16 + lm) * 32 + lq * 8];
      bfr[s4] = *(const bf16x8*)&Bs[(wn + s4 * 16 + lm) * 32 + lq * 8];
    }
#pragma unroll
    for (int ms = 0; ms < 4; ++ms)
#pragma unroll
      for (int ns = 0; ns < 4; ++ns)
        acc[ms][ns] = MFMA16(af[ms], bfr[ns], acc[ms][ns]);
    __syncthreads();
  }

#pragma unroll
  for (int ms = 0; ms < 4; ++ms) {
#pragma unroll
    for (int r = 0; r < 4; ++r) {
      int row = m0 + wm + ms * 16 + lq * 4 + r;
      int w = row >> 8, n = row & 255;
      int b = w >> 4, wh = (w >> 2) & 3, ww = w & 3;
      int rh = n >> 4, rw = n & 15;
      int l = wh * 1024 + rh * 64 + ww * 16 + rw;
      size_t obase = (size_t)(b * 4096 + l) * 512;
#pragma unroll
      for (int ns = 0; ns < 4; ++ns) {
        int col = n0 + wn + ns * 16 + lm;
        out[obase + col] = acc[ms][ns][r] + bp[col];
      }
    }
  }
}

// ---------------------------------------------------------------------------
// K5 fallback: fp32-Wp proj GEMM (original).
// ---------------------------------------------------------------------------
__global__ __launch_bounds__(256) void k_proj(const bf16_t* __restrict__ A,
                                              const float* __restrict__ Wp,
                                              const float* __restrict__ bp,
                                              float* __restrict__ out) {
  __shared__ __align__(16) bf16_t As[128 * LDAB];
  __shared__ __align__(16) bf16_t Bs[128 * LDAB];

  const int tid = threadIdx.x;
  const int m0 = blockIdx.x * 128;
  const int n0 = blockIdx.y * 128;
  const int lane = tid & 63, wid = tid >> 6;
  const int wm = (wid >> 1) * 64, wn = (wid & 1) * 64;
  const int lm = lane & 15, lq = lane >> 4;

  size_t abase[2];
#pragma unroll
  for (int i = 0; i < 2; ++i) {
    int id = tid + 256 * i;
    int r = m0 + (id >> 2);
    int w = r >> 8, n = r & 255;
    abase[i] = (size_t)w * 131072 + (size_t)n * 64 + (id & 3) * 8;
  }
  const float* bptr[4];
#pragma unroll
  for (int i = 0; i < 4; ++i) {
    int id = tid + 256 * i;
    bptr[i] = Wp + (size_t)(n0 + (id >> 3)) * 512 + (id & 7) * 4;
  }

  floatx4 acc[4][4] = {};

  for (int k0 = 0; k0 < 512; k0 += 32) {
#pragma unroll
    for (int i = 0; i < 2; ++i) {
      int id = tid + 256 * i;
      bf16x8 av = *(const bf16x8*)(A + abase[i] + (k0 >> 6) * 16384 + (k0 & 63));
      *(bf16x8*)&As[(id >> 2) * LDAB + (id & 3) * 8] = av;
    }
#pragma unroll
    for (int i = 0; i < 4; ++i) {
      int id = tid + 256 * i;
      float4 bv = *(const float4*)(bptr[i] + k0);
      *(bf16x4*)&Bs[(id >> 3) * LDAB + (id & 7) * 4] = cvt4(bv);
    }
    __syncthreads();
    bf16x8 af[4], bfr[4];
#pragma unroll
    for (int s = 0; s < 4; ++s) {
      af[s]  = *(const bf16x8*)&As[(wm + s * 16 + lm) * LDAB + lq * 8];
      bfr[s] = *(const bf16x8*)&Bs[(wn + s * 16 + lm) * LDAB + lq * 8];
    }
#pragma unroll
    for (int ms = 0; ms < 4; ++ms)
#pragma unroll
      for (int ns = 0; ns < 4; ++ns)
        acc[ms][ns] = MFMA16(af[ms], bfr[ns], acc[ms][ns]);
    __syncthreads();
  }

#pragma unroll
  for (int ms = 0; ms < 4; ++ms) {
#pragma unroll
    for (int r = 0; r < 4; ++r) {
      int row = m0 + wm + ms * 16 + lq * 4 + r;
      int w = row >> 8, n = row & 255;
      int b = w >> 4, wh = (w >> 2) & 3, ww = w & 3;
      int rh = n >> 4, rw = n & 15;
      int l = wh * 1024 + rh * 64 + ww * 16 + rw;
      size_t obase = (size_t)(b * 4096 + l) * 512;
#pragma unroll
      for (int ns = 0; ns < 4; ++ns) {
        int col = n0 + wn + ns * 16 + lm;
        out[obase + col] = acc[ms][ns][r] + bp[col];
      }
    }
  }
}

// ---------------------------------------------------------------------------
extern "C" void kernel_launch(void* const* d_in, const int* in_sizes, int n_in,
                              void* d_out, int out_size, void* d_ws, size_t ws_size,
                              hipStream_t stream) {
  const float* x     = (const float*)d_in[0];
  const float* qkvw  = (const float*)d_in[1];
  const float* qkvb  = (const float*)d_in[2];
  const float* projw = (const float*)d_in[3];
  const float* projb = (const float*)d_in[4];
  const float* rbt   = (const float*)d_in[5];
  const float* pew   = (const float*)d_in[6];
  const float* peb   = (const float*)d_in[7];
  const int*   ridx  = (const int*)d_in[8];
  float* out = (float*)d_out;

  char* ws = (char*)d_ws;
  bf16_t* bias = (bf16_t*)ws;                                //  1 MiB bf16
  bf16_t* q    = (bf16_t*)(ws + (2u << 20));                 // 32 MiB
  bf16_t* k    = (bf16_t*)(ws + (2u << 20) + 33554432u);     // 32 MiB
  bf16_t* v    = (bf16_t*)(ws + (2u << 20) + 67108864u);     // 32 MiB
  const size_t need  = 2097152u + 4u * 33554432u;            // 130 MiB
  bf16_t* xb    = (bf16_t*)(ws + 136314880u);                // @130 MiB, 32 MiB
  bf16_t* wqkvb = (bf16_t*)(ws + 169869312u);                // @162 MiB, 1.5 MiB
  bf16_t* wpb   = (bf16_t*)(ws + 171442176u);                // @163.5 MiB, 0.5 MiB
  const size_t need2 = 171966464u;                           // 164 MiB

  if (ws_size >= need2) {
    k_prep<<<3328, 256, 0, stream>>>(x, xb, qkvw, wqkvb, projw, wpb,
                                     ridx, rbt, bias);
    bf16_t* o = (bf16_t*)(ws + (2u << 20) + 100663296u);     // @98 MiB
    k_qkv_b<<<3072, 256, 0, stream>>>(xb, wqkvb, qkvb, q, k, v);
    k_attn_t<<<1024, 256, 0, stream>>>(q, k, v, o, bias, pew, peb);
    k_proj_b<<<1024, 256, 0, stream>>>(o, wpb, projb, out);
  } else if (ws_size >= need) {
    k_bias<<<256, 256, 0, stream>>>(ridx, rbt, bias);
    bf16_t* o = (bf16_t*)(ws + (2u << 20) + 100663296u);     // @98 MiB
    k_qkv<<<dim3(256, 12), 256, 0, stream>>>(x, qkvw, qkvb, q, k, v);
    k_attn_t<<<1024, 256, 0, stream>>>(q, k, v, o, bias, pew, peb);
    k_proj<<<dim3(256, 4), 256, 0, stream>>>(o, projw, projb, out);
  } else {
    k_bias<<<256, 256, 0, stream>>>(ridx, rbt, bias);
    k_qkv<<<dim3(256, 12), 256, 0, stream>>>(x, qkvw, qkvb, q, k, v);
    k_attn_s<<<1024, 256, 0, stream>>>(q, k, v, bias, pew, peb);
    k_proj<<<dim3(256, 4), 256, 0, stream>>>(v, projw, projb, out);
  }
}